// Round 5
// baseline (288.433 us; speedup 1.0000x reference)
//
#include <hip/hip_runtime.h>
#include <hip/hip_bf16.h>

#define ALPHA 0.1f

using bf16x8 = __attribute__((ext_vector_type(8))) short;
using f32x4  = __attribute__((ext_vector_type(4))) float;

__device__ __forceinline__ unsigned short f2bf(float f) {
    unsigned u = __builtin_bit_cast(unsigned, f);
    u += 0x7fff + ((u >> 16) & 1);               // round-to-nearest-even
    return (unsigned short)(u >> 16);
}
__device__ __forceinline__ float bf2f(unsigned short h) {
    unsigned u = ((unsigned)h) << 16;
    return __builtin_bit_cast(float, u);
}
__device__ __forceinline__ float bflo(unsigned v) {
    return __builtin_bit_cast(float, v << 16);
}
__device__ __forceinline__ float bfhi(unsigned v) {
    return __builtin_bit_cast(float, v & 0xffff0000u);
}

// ---------------- edge preprocessing ----------------

__global__ void deg_kernel(const int* __restrict__ ei, int* __restrict__ cnt, int E) {
    int e = blockIdx.x * blockDim.x + threadIdx.x;
    if (e >= E) return;
    atomicAdd(&cnt[ei[E + e]], 1);
}

// per-wave atomic segment allocator + dinv (segments need only be contiguous, not ordered)
__global__ void alloc_kernel(const int* __restrict__ cnt, int* __restrict__ roff,
                             float* __restrict__ dinv, int* __restrict__ cursor, int N) {
    int i = blockIdx.x * blockDim.x + threadIdx.x;
    int lane = threadIdx.x & 63;
    int c = (i < N) ? cnt[i] : 0;
    if (i < N) dinv[i] = 1.0f / sqrtf((float)(c + 1));   // +1 self loop
    int pre = c;
#pragma unroll
    for (int off = 1; off < 64; off <<= 1) {
        int t = __shfl_up(pre, off, 64);
        if (lane >= off) pre += t;
    }
    int total = __shfl(pre, 63, 64);
    int base = 0;
    if (lane == 0) base = atomicAdd(cursor, total);
    base = __shfl(base, 0, 64);
    if (i < N) roff[i] = base + pre - c;
}

// claim slot directly from roff (roff[d] ends at segment END = start + cnt[d])
__global__ void fill_kernel(const int* __restrict__ ei, int* __restrict__ roff,
                            int* __restrict__ col, int E) {
    int e = blockIdx.x * blockDim.x + threadIdx.x;
    if (e >= E) return;
    int s = ei[e], d = ei[E + e];
    int pos = atomicAdd(&roff[d], 1);
    col[pos] = s;
}

// ---------------- xs = bf16(dinv[n] * x[n])  [N][128] packed as uint pairs ----------------

__global__ void xsconv_kernel(const float4* __restrict__ x4, const float* __restrict__ dinv,
                              uint2* __restrict__ xs, int total) {   // total = N*32
    int i = blockIdx.x * blockDim.x + threadIdx.x;
    if (i >= total) return;
    float di = dinv[i >> 5];
    float4 v = x4[i];
    uint2 o;
    o.x = (unsigned)f2bf(di * v.x) | ((unsigned)f2bf(di * v.y) << 16);
    o.y = (unsigned)f2bf(di * v.z) | ((unsigned)f2bf(di * v.w) << 16);
    xs[i] = o;
}

// ---------------- aggregation: one wave per node, bf16 gather, split hi/lo output ----------------

__global__ void agg_kernel(const unsigned* __restrict__ xs, const int* __restrict__ col,
                           const int* __restrict__ roff, const int* __restrict__ cnt,
                           const float* __restrict__ dinv,
                           unsigned* __restrict__ agg_hi, unsigned* __restrict__ agg_lo, int N) {
    int w = (blockIdx.x * blockDim.x + threadIdx.x) >> 6;
    int lane = threadIdx.x & 63;
    if (w >= N) return;
    float di = dinv[w];
    unsigned vself = xs[(size_t)w * 64 + lane];
    float ax = bflo(vself), ay = bfhi(vself);      // self term
    int e = roff[w];            // segment end (after fill's claims)
    int s = e - cnt[w];
    int j = s;
    for (; j + 4 <= e; j += 4) {
        int c0 = col[j], c1 = col[j + 1], c2 = col[j + 2], c3 = col[j + 3];
        unsigned v0 = xs[(size_t)c0 * 64 + lane];
        unsigned v1 = xs[(size_t)c1 * 64 + lane];
        unsigned v2 = xs[(size_t)c2 * 64 + lane];
        unsigned v3 = xs[(size_t)c3 * 64 + lane];
        ax += bflo(v0) + bflo(v1) + bflo(v2) + bflo(v3);
        ay += bfhi(v0) + bfhi(v1) + bfhi(v2) + bfhi(v3);
    }
    for (; j < e; ++j) {
        unsigned v = xs[(size_t)col[j] * 64 + lane];
        ax += bflo(v);
        ay += bfhi(v);
    }
    float g0 = di * ax, g1 = di * ay;
    unsigned short h0 = f2bf(g0), h1 = f2bf(g1);
    unsigned short l0 = f2bf(g0 - bf2f(h0)), l1 = f2bf(g1 - bf2f(h1));
    agg_hi[(size_t)w * 64 + lane] = (unsigned)h0 | ((unsigned)h1 << 16);
    agg_lo[(size_t)w * 64 + lane] = (unsigned)l0 | ((unsigned)l1 << 16);
}

// ---------------- fold W_gcn@W1 -> Wc [128,256], bc = b_gcn@W1 + b1 ----------------

__global__ void wcbc_kernel(const float* __restrict__ Wg, const float* __restrict__ bg,
                            const float* __restrict__ W1, const float* __restrict__ b1,
                            float* __restrict__ Wc, float* __restrict__ bc) {
    int n = threadIdx.x;
    int m = blockIdx.x;
    if (m < 128) {
        float acc = 0.f;
#pragma unroll 8
        for (int k = 0; k < 512; ++k) acc += Wg[m * 512 + k] * W1[k * 256 + n];
        Wc[m * 256 + n] = acc;
    } else {
        float acc = b1[n];
#pragma unroll 8
        for (int k = 0; k < 512; ++k) acc += bg[k] * W1[k * 256 + n];
        bc[n] = acc;
    }
}

// ---------------- transpose+split weights: W[K][Nn] fp32 -> Wt_hi/lo [Nn][K] bf16 ----------------

__global__ void tsplit_kernel(const float* __restrict__ W, unsigned short* __restrict__ hi,
                              unsigned short* __restrict__ lo, int K, int Nn) {
    int idx = blockIdx.x * blockDim.x + threadIdx.x;
    if (idx >= K * Nn) return;
    int n = idx / K, k = idx - n * K;
    float v = W[k * Nn + n];
    unsigned short h = f2bf(v);
    hi[idx] = h;
    lo[idx] = f2bf(v - bf2f(h));
}

// ---------------- fused MLP: agg -> h1 -> h2 -> h3 -> head, one block per 128 rows ----------------
// 8 waves (2 row-groups x 4 col-groups); wave tile 64x64 = 4x4 frags of 16x16x32.
// A/B frags read DIRECTLY from global (line-coalesced 16B/lane, weights L2-resident).
// h1/h2 live in one 64KB LDS buffer (bf16, XOR-swizzled col ^= (row&7)*8), h2 overwrites h1.
// Stage1: A=agg split hi/lo (3-pass). Stages 2/3: A=h bf16 (2-pass), B always split hi/lo.

__global__ __launch_bounds__(512, 2) void mlp_fused(
    const unsigned short* __restrict__ AHi, const unsigned short* __restrict__ ALo,
    const unsigned short* __restrict__ WcHi, const unsigned short* __restrict__ WcLo,
    const unsigned short* __restrict__ W2Hi, const unsigned short* __restrict__ W2Lo,
    const unsigned short* __restrict__ W3Hi, const unsigned short* __restrict__ W3Lo,
    const float* __restrict__ bc, const float* __restrict__ b2, const float* __restrict__ b3,
    const float* __restrict__ wo, const float* __restrict__ bo,
    float* __restrict__ outv, int M)
{
    __shared__ unsigned short hbuf[128][256];   // 64 KB, swizzled

    const int tid  = threadIdx.x;
    const int lane = tid & 63;
    const int wid  = tid >> 6;
    const int wr = wid >> 2, wc = wid & 3;
    const int l15 = lane & 15, l4 = lane >> 4;
    const int koff = l4 * 8;
    const int m0 = blockIdx.x * 128;
    const int rb = wr * 64, cb = wc * 64;

    f32x4 acc[4][4] = {};

    size_t arow[4];
#pragma unroll
    for (int mi = 0; mi < 4; ++mi) {
        int gm = m0 + rb + mi * 16 + l15;
        arow[mi] = (size_t)(gm < M ? gm : M - 1);
    }
    int bcol[4];
#pragma unroll
    for (int ni = 0; ni < 4; ++ni) bcol[ni] = cb + ni * 16 + l15;

    // ---- stage 1: K=128, A=agg hi/lo, B=Wc hi/lo, 3-pass ----
    for (int k0 = 0; k0 < 128; k0 += 32) {
        bf16x8 af[4], al[4], bh[4], bl[4];
#pragma unroll
        for (int mi = 0; mi < 4; ++mi) {
            af[mi] = *reinterpret_cast<const bf16x8*>(&AHi[arow[mi] * 128 + k0 + koff]);
            al[mi] = *reinterpret_cast<const bf16x8*>(&ALo[arow[mi] * 128 + k0 + koff]);
        }
#pragma unroll
        for (int ni = 0; ni < 4; ++ni) {
            bh[ni] = *reinterpret_cast<const bf16x8*>(&WcHi[(size_t)bcol[ni] * 128 + k0 + koff]);
            bl[ni] = *reinterpret_cast<const bf16x8*>(&WcLo[(size_t)bcol[ni] * 128 + k0 + koff]);
        }
#pragma unroll
        for (int mi = 0; mi < 4; ++mi)
#pragma unroll
            for (int ni = 0; ni < 4; ++ni)
                acc[mi][ni] = __builtin_amdgcn_mfma_f32_16x16x32_bf16(af[mi], bh[ni], acc[mi][ni], 0, 0, 0);
#pragma unroll
        for (int mi = 0; mi < 4; ++mi)
#pragma unroll
            for (int ni = 0; ni < 4; ++ni)
                acc[mi][ni] = __builtin_amdgcn_mfma_f32_16x16x32_bf16(af[mi], bl[ni], acc[mi][ni], 0, 0, 0);
#pragma unroll
        for (int mi = 0; mi < 4; ++mi)
#pragma unroll
            for (int ni = 0; ni < 4; ++ni)
                acc[mi][ni] = __builtin_amdgcn_mfma_f32_16x16x32_bf16(al[mi], bh[ni], acc[mi][ni], 0, 0, 0);
    }
    // epilogue 1 -> LDS (bf16, swizzled)
#pragma unroll
    for (int ni = 0; ni < 4; ++ni) {
        float bb = bc[cb + ni * 16 + l15];
#pragma unroll
        for (int mi = 0; mi < 4; ++mi)
#pragma unroll
            for (int r = 0; r < 4; ++r) {
                int row = rb + mi * 16 + l4 * 4 + r;
                int colx = (cb + ni * 16 + l15) ^ ((row & 7) << 3);
                float v = acc[mi][ni][r] + bb;
                v = v > 0.f ? v : ALPHA * v;
                hbuf[row][colx] = f2bf(v);
            }
    }
    __syncthreads();

    // ---- stage 2: K=256, A=h1 (LDS bf16), B=W2 hi/lo, 2-pass ----
#pragma unroll
    for (int mi = 0; mi < 4; ++mi)
#pragma unroll
        for (int ni = 0; ni < 4; ++ni)
            acc[mi][ni] = f32x4{0.f, 0.f, 0.f, 0.f};

    for (int k0 = 0; k0 < 256; k0 += 32) {
        bf16x8 a[4], bh[4], bl[4];
#pragma unroll
        for (int mi = 0; mi < 4; ++mi) {
            int row = rb + mi * 16 + l15;
            a[mi] = *reinterpret_cast<const bf16x8*>(&hbuf[row][(k0 + koff) ^ ((row & 7) << 3)]);
        }
#pragma unroll
        for (int ni = 0; ni < 4; ++ni) {
            bh[ni] = *reinterpret_cast<const bf16x8*>(&W2Hi[(size_t)bcol[ni] * 256 + k0 + koff]);
            bl[ni] = *reinterpret_cast<const bf16x8*>(&W2Lo[(size_t)bcol[ni] * 256 + k0 + koff]);
        }
#pragma unroll
        for (int mi = 0; mi < 4; ++mi)
#pragma unroll
            for (int ni = 0; ni < 4; ++ni)
                acc[mi][ni] = __builtin_amdgcn_mfma_f32_16x16x32_bf16(a[mi], bh[ni], acc[mi][ni], 0, 0, 0);
#pragma unroll
        for (int mi = 0; mi < 4; ++mi)
#pragma unroll
            for (int ni = 0; ni < 4; ++ni)
                acc[mi][ni] = __builtin_amdgcn_mfma_f32_16x16x32_bf16(a[mi], bl[ni], acc[mi][ni], 0, 0, 0);
    }
    __syncthreads();   // all h1 reads done
    // epilogue 2 -> overwrite LDS
#pragma unroll
    for (int ni = 0; ni < 4; ++ni) {
        float bb = b2[cb + ni * 16 + l15];
#pragma unroll
        for (int mi = 0; mi < 4; ++mi)
#pragma unroll
            for (int r = 0; r < 4; ++r) {
                int row = rb + mi * 16 + l4 * 4 + r;
                int colx = (cb + ni * 16 + l15) ^ ((row & 7) << 3);
                float v = acc[mi][ni][r] + bb;
                v = v > 0.f ? v : ALPHA * v;
                hbuf[row][colx] = f2bf(v);
            }
    }
    __syncthreads();

    // ---- stage 3: K=256, A=h2 (LDS), B=W3 hi/lo, 2-pass; fused head epilogue ----
#pragma unroll
    for (int mi = 0; mi < 4; ++mi)
#pragma unroll
        for (int ni = 0; ni < 4; ++ni)
            acc[mi][ni] = f32x4{0.f, 0.f, 0.f, 0.f};

    for (int k0 = 0; k0 < 256; k0 += 32) {
        bf16x8 a[4], bh[4], bl[4];
#pragma unroll
        for (int mi = 0; mi < 4; ++mi) {
            int row = rb + mi * 16 + l15;
            a[mi] = *reinterpret_cast<const bf16x8*>(&hbuf[row][(k0 + koff) ^ ((row & 7) << 3)]);
        }
#pragma unroll
        for (int ni = 0; ni < 4; ++ni) {
            bh[ni] = *reinterpret_cast<const bf16x8*>(&W3Hi[(size_t)bcol[ni] * 256 + k0 + koff]);
            bl[ni] = *reinterpret_cast<const bf16x8*>(&W3Lo[(size_t)bcol[ni] * 256 + k0 + koff]);
        }
#pragma unroll
        for (int mi = 0; mi < 4; ++mi)
#pragma unroll
            for (int ni = 0; ni < 4; ++ni)
                acc[mi][ni] = __builtin_amdgcn_mfma_f32_16x16x32_bf16(a[mi], bh[ni], acc[mi][ni], 0, 0, 0);
#pragma unroll
        for (int mi = 0; mi < 4; ++mi)
#pragma unroll
            for (int ni = 0; ni < 4; ++ni)
                acc[mi][ni] = __builtin_amdgcn_mfma_f32_16x16x32_bf16(a[mi], bl[ni], acc[mi][ni], 0, 0, 0);
    }

    // head: out[m] = sum_n leaky(h3[m,n]) * wo[n]  (+ bo once per row, from wc==0)
    float bn[4], wn[4];
#pragma unroll
    for (int ni = 0; ni < 4; ++ni) {
        int gn = cb + ni * 16 + l15;
        bn[ni] = b3[gn];
        wn[ni] = wo[gn];
    }
    float badd = (wc == 0) ? bo[0] : 0.f;
#pragma unroll
    for (int mi = 0; mi < 4; ++mi) {
#pragma unroll
        for (int r = 0; r < 4; ++r) {
            float p = 0.f;
#pragma unroll
            for (int ni = 0; ni < 4; ++ni) {
                float v = acc[mi][ni][r] + bn[ni];
                v = v > 0.f ? v : ALPHA * v;
                p += v * wn[ni];
            }
#pragma unroll
            for (int off = 1; off < 16; off <<= 1) p += __shfl_xor(p, off, 16);
            int gm = m0 + rb + mi * 16 + l4 * 4 + r;
            if (l15 == 0 && gm < M) atomicAdd(&outv[gm], p + badd);
        }
    }
}

// ---------------- launch ----------------

extern "C" void kernel_launch(void* const* d_in, const int* in_sizes, int n_in,
                              void* d_out, int out_size, void* d_ws, size_t ws_size,
                              hipStream_t stream) {
    const float* x  = (const float*)d_in[0];
    const int*   ei = (const int*)d_in[1];
    const float* Wg = (const float*)d_in[2];
    const float* bg = (const float*)d_in[3];
    const float* W1 = (const float*)d_in[4];
    const float* b1 = (const float*)d_in[5];
    const float* W2 = (const float*)d_in[6];
    const float* b2 = (const float*)d_in[7];
    const float* W3 = (const float*)d_in[8];
    const float* b3 = (const float*)d_in[9];
    const float* Wo = (const float*)d_in[10];
    const float* bo = (const float*)d_in[11];
    float* out = (float*)d_out;

    const int N = in_sizes[0] / 128;   // 50000
    const int E = in_sizes[1] / 2;     // 800000

    char* ws = (char*)d_ws;
    unsigned* xs     = (unsigned*)ws; ws += (size_t)N * 64 * 4;
    unsigned* aggHi  = (unsigned*)ws; ws += (size_t)N * 64 * 4;
    unsigned* aggLo  = (unsigned*)ws; ws += (size_t)N * 64 * 4;
    int* col   = (int*)ws;    ws += (size_t)E * 4;
    int* cnt   = (int*)ws;    ws += (size_t)N * 4;
    int* cursor= (int*)ws;    ws += 64;              // contiguous with cnt -> one memset
    int* roff  = (int*)ws;    ws += (size_t)(N + 64) * 4;
    float* dinv= (float*)ws;  ws += (size_t)N * 4;
    float* Wc  = (float*)ws;  ws += 128 * 256 * 4;
    float* bc  = (float*)ws;  ws += 256 * 4;
    unsigned short* WcThi = (unsigned short*)ws; ws += 256 * 128 * 2;
    unsigned short* WcTlo = (unsigned short*)ws; ws += 256 * 128 * 2;
    unsigned short* W2Thi = (unsigned short*)ws; ws += 256 * 256 * 2;
    unsigned short* W2Tlo = (unsigned short*)ws; ws += 256 * 256 * 2;
    unsigned short* W3Thi = (unsigned short*)ws; ws += 256 * 256 * 2;
    unsigned short* W3Tlo = (unsigned short*)ws; ws += 256 * 256 * 2;

    hipMemsetAsync(cnt, 0, (size_t)N * 4 + 64, stream);   // cnt + cursor
    hipMemsetAsync(out, 0, (size_t)N * 4, stream);        // head accumulates

    deg_kernel  <<<(E + 255) / 256, 256, 0, stream>>>(ei, cnt, E);
    alloc_kernel<<<(N + 255) / 256, 256, 0, stream>>>(cnt, roff, dinv, cursor, N);
    fill_kernel <<<(E + 255) / 256, 256, 0, stream>>>(ei, roff, col, E);
    xsconv_kernel<<<(N * 32 + 255) / 256, 256, 0, stream>>>((const float4*)x, dinv, (uint2*)xs, N * 32);
    agg_kernel  <<<(N + 3) / 4, 256, 0, stream>>>(xs, col, roff, cnt, dinv, aggHi, aggLo, N);

    wcbc_kernel<<<129, 256, 0, stream>>>(Wg, bg, W1, b1, Wc, bc);
    tsplit_kernel<<<(128 * 256 + 255) / 256, 256, 0, stream>>>(Wc, WcThi, WcTlo, 128, 256);
    tsplit_kernel<<<(256 * 256 + 255) / 256, 256, 0, stream>>>(W2, W2Thi, W2Tlo, 256, 256);
    tsplit_kernel<<<(256 * 256 + 255) / 256, 256, 0, stream>>>(W3, W3Thi, W3Tlo, 256, 256);

    mlp_fused<<<(N + 127) / 128, 512, 0, stream>>>(
        (const unsigned short*)aggHi, (const unsigned short*)aggLo,
        WcThi, WcTlo, W2Thi, W2Tlo, W3Thi, W3Tlo,
        bc, b2, b3, Wo, bo, out, N);
}

// Round 6
// 286.048 us; speedup vs baseline: 1.0083x; 1.0083x over previous
//
#include <hip/hip_runtime.h>
#include <hip/hip_bf16.h>

#define ALPHA 0.1f

using bf16x8 = __attribute__((ext_vector_type(8))) short;
using f32x4  = __attribute__((ext_vector_type(4))) float;

__device__ __forceinline__ unsigned short f2bf(float f) {
    unsigned u = __builtin_bit_cast(unsigned, f);
    u += 0x7fff + ((u >> 16) & 1);               // round-to-nearest-even
    return (unsigned short)(u >> 16);
}
__device__ __forceinline__ float bf2f(unsigned short h) {
    unsigned u = ((unsigned)h) << 16;
    return __builtin_bit_cast(float, u);
}
__device__ __forceinline__ float bflo(unsigned v) {
    return __builtin_bit_cast(float, v << 16);
}
__device__ __forceinline__ float bfhi(unsigned v) {
    return __builtin_bit_cast(float, v & 0xffff0000u);
}

// ---------------- edge preprocessing ----------------

__global__ void deg_kernel(const int* __restrict__ ei, int* __restrict__ cnt, int E) {
    int e = blockIdx.x * blockDim.x + threadIdx.x;
    if (e >= E) return;
    atomicAdd(&cnt[ei[E + e]], 1);
}

// per-wave atomic segment allocator + dinv (segments need only be contiguous, not ordered)
__global__ void alloc_kernel(const int* __restrict__ cnt, int* __restrict__ roff,
                             float* __restrict__ dinv, int* __restrict__ cursor, int N) {
    int i = blockIdx.x * blockDim.x + threadIdx.x;
    int lane = threadIdx.x & 63;
    int c = (i < N) ? cnt[i] : 0;
    if (i < N) dinv[i] = 1.0f / sqrtf((float)(c + 1));   // +1 self loop
    int pre = c;
#pragma unroll
    for (int off = 1; off < 64; off <<= 1) {
        int t = __shfl_up(pre, off, 64);
        if (lane >= off) pre += t;
    }
    int total = __shfl(pre, 63, 64);
    int base = 0;
    if (lane == 0) base = atomicAdd(cursor, total);
    base = __shfl(base, 0, 64);
    if (i < N) roff[i] = base + pre - c;
}

// claim slot directly from roff (roff[d] ends at segment END = start + cnt[d])
__global__ void fill_kernel(const int* __restrict__ ei, int* __restrict__ roff,
                            int* __restrict__ col, int E) {
    int e = blockIdx.x * blockDim.x + threadIdx.x;
    if (e >= E) return;
    int s = ei[e], d = ei[E + e];
    int pos = atomicAdd(&roff[d], 1);
    col[pos] = s;
}

// ---------------- xs = bf16(dinv[n] * x[n])  [N][128] packed as uint pairs ----------------

__global__ void xsconv_kernel(const float4* __restrict__ x4, const float* __restrict__ dinv,
                              uint2* __restrict__ xs, int total) {   // total = N*32
    int i = blockIdx.x * blockDim.x + threadIdx.x;
    if (i >= total) return;
    float di = dinv[i >> 5];
    float4 v = x4[i];
    uint2 o;
    o.x = (unsigned)f2bf(di * v.x) | ((unsigned)f2bf(di * v.y) << 16);
    o.y = (unsigned)f2bf(di * v.z) | ((unsigned)f2bf(di * v.w) << 16);
    xs[i] = o;
}

// ---------------- aggregation: one wave per node, bf16 gather, split hi/lo output ----------------

__global__ void agg_kernel(const unsigned* __restrict__ xs, const int* __restrict__ col,
                           const int* __restrict__ roff, const int* __restrict__ cnt,
                           const float* __restrict__ dinv,
                           unsigned* __restrict__ agg_hi, unsigned* __restrict__ agg_lo, int N) {
    int w = (blockIdx.x * blockDim.x + threadIdx.x) >> 6;
    int lane = threadIdx.x & 63;
    if (w >= N) return;
    float di = dinv[w];
    unsigned vself = xs[(size_t)w * 64 + lane];
    float ax = bflo(vself), ay = bfhi(vself);      // self term
    int e = roff[w];            // segment end (after fill's claims)
    int s = e - cnt[w];
    int j = s;
    for (; j + 4 <= e; j += 4) {
        int c0 = col[j], c1 = col[j + 1], c2 = col[j + 2], c3 = col[j + 3];
        unsigned v0 = xs[(size_t)c0 * 64 + lane];
        unsigned v1 = xs[(size_t)c1 * 64 + lane];
        unsigned v2 = xs[(size_t)c2 * 64 + lane];
        unsigned v3 = xs[(size_t)c3 * 64 + lane];
        ax += bflo(v0) + bflo(v1) + bflo(v2) + bflo(v3);
        ay += bfhi(v0) + bfhi(v1) + bfhi(v2) + bfhi(v3);
    }
    for (; j < e; ++j) {
        unsigned v = xs[(size_t)col[j] * 64 + lane];
        ax += bflo(v);
        ay += bfhi(v);
    }
    float g0 = di * ax, g1 = di * ay;
    unsigned short h0 = f2bf(g0), h1 = f2bf(g1);
    unsigned short l0 = f2bf(g0 - bf2f(h0)), l1 = f2bf(g1 - bf2f(h1));
    agg_hi[(size_t)w * 64 + lane] = (unsigned)h0 | ((unsigned)h1 << 16);
    agg_lo[(size_t)w * 64 + lane] = (unsigned)l0 | ((unsigned)l1 << 16);
}

// ---------------- fold W_gcn@W1 -> Wc [128,256], bc = b_gcn@W1 + b1 ----------------

__global__ void wcbc_kernel(const float* __restrict__ Wg, const float* __restrict__ bg,
                            const float* __restrict__ W1, const float* __restrict__ b1,
                            float* __restrict__ Wc, float* __restrict__ bc) {
    int n = threadIdx.x;
    int m = blockIdx.x;
    if (m < 128) {
        float acc = 0.f;
#pragma unroll 8
        for (int k = 0; k < 512; ++k) acc += Wg[m * 512 + k] * W1[k * 256 + n];
        Wc[m * 256 + n] = acc;
    } else {
        float acc = b1[n];
#pragma unroll 8
        for (int k = 0; k < 512; ++k) acc += bg[k] * W1[k * 256 + n];
        bc[n] = acc;
    }
}

// ---------------- transpose+split weights: W[K][Nn] fp32 -> Wt_hi/lo [Nn][K] bf16 ----------------

__global__ void tsplit_kernel(const float* __restrict__ W, unsigned short* __restrict__ hi,
                              unsigned short* __restrict__ lo, int K, int Nn) {
    int idx = blockIdx.x * blockDim.x + threadIdx.x;
    if (idx >= K * Nn) return;
    int n = idx / K, k = idx - n * K;
    float v = W[k * Nn + n];
    unsigned short h = f2bf(v);
    hi[idx] = h;
    lo[idx] = f2bf(v - bf2f(h));
}

// ---------------- fused MLP: agg -> h1 -> h2 -> h3 -> head, one block per 64 rows ----------------
// 8 waves = 1 row-group x 8 col-groups; wave tile 64x32 = 4x2 frags of 16x16x32.
// B fragments loaded once per block (no cross-wave redundancy), rotating 1-deep prefetch.
// A/B direct from global/L2 (no barriers inside k-loops -> scheduler hoists freely).
// h1/h2 live in one 32KB LDS buffer (bf16, XOR-swizzled col ^= (row&7)*8).

__global__ __launch_bounds__(512, 4) void mlp_fused(
    const unsigned short* __restrict__ AHi, const unsigned short* __restrict__ ALo,
    const unsigned short* __restrict__ WcHi, const unsigned short* __restrict__ WcLo,
    const unsigned short* __restrict__ W2Hi, const unsigned short* __restrict__ W2Lo,
    const unsigned short* __restrict__ W3Hi, const unsigned short* __restrict__ W3Lo,
    const float* __restrict__ bc, const float* __restrict__ b2, const float* __restrict__ b3,
    const float* __restrict__ wo, const float* __restrict__ bo,
    float* __restrict__ outv, int M)
{
    __shared__ unsigned short hbuf[64][256];   // 32 KB, swizzled

    const int tid  = threadIdx.x;
    const int lane = tid & 63;
    const int wc   = tid >> 6;                 // wave id = col-group (0..7)
    const int l15 = lane & 15, l4 = lane >> 4;
    const int koff = l4 * 8;
    const int m0 = blockIdx.x * 64;
    const int cb = wc * 32;

    f32x4 acc[4][2];

    size_t arow[4];
#pragma unroll
    for (int mi = 0; mi < 4; ++mi) {
        int gm = m0 + mi * 16 + l15;
        arow[mi] = (size_t)(gm < M ? gm : M - 1);
    }
    int bcol[2];
#pragma unroll
    for (int ni = 0; ni < 2; ++ni) bcol[ni] = cb + ni * 16 + l15;

    // ================= stage 1: K=128, A=agg hi/lo (3-pass) =================
#pragma unroll
    for (int mi = 0; mi < 4; ++mi)
#pragma unroll
        for (int ni = 0; ni < 2; ++ni) acc[mi][ni] = f32x4{0.f, 0.f, 0.f, 0.f};

    {
        bf16x8 bh[2], bl[2];
#pragma unroll
        for (int ni = 0; ni < 2; ++ni) {
            bh[ni] = *reinterpret_cast<const bf16x8*>(&WcHi[(size_t)bcol[ni] * 128 + koff]);
            bl[ni] = *reinterpret_cast<const bf16x8*>(&WcLo[(size_t)bcol[ni] * 128 + koff]);
        }
#pragma unroll
        for (int ks = 0; ks < 4; ++ks) {
            const int k0 = ks * 32;
            bf16x8 af[4], al[4];
#pragma unroll
            for (int mi = 0; mi < 4; ++mi) {
                af[mi] = *reinterpret_cast<const bf16x8*>(&AHi[arow[mi] * 128 + k0 + koff]);
                al[mi] = *reinterpret_cast<const bf16x8*>(&ALo[arow[mi] * 128 + k0 + koff]);
            }
            bf16x8 bhN[2] = {bh[0], bh[1]}, blN[2] = {bl[0], bl[1]};
            if (ks < 3) {
#pragma unroll
                for (int ni = 0; ni < 2; ++ni) {
                    bhN[ni] = *reinterpret_cast<const bf16x8*>(&WcHi[(size_t)bcol[ni] * 128 + k0 + 32 + koff]);
                    blN[ni] = *reinterpret_cast<const bf16x8*>(&WcLo[(size_t)bcol[ni] * 128 + k0 + 32 + koff]);
                }
            }
#pragma unroll
            for (int mi = 0; mi < 4; ++mi)
#pragma unroll
                for (int ni = 0; ni < 2; ++ni)
                    acc[mi][ni] = __builtin_amdgcn_mfma_f32_16x16x32_bf16(af[mi], bh[ni], acc[mi][ni], 0, 0, 0);
#pragma unroll
            for (int mi = 0; mi < 4; ++mi)
#pragma unroll
                for (int ni = 0; ni < 2; ++ni)
                    acc[mi][ni] = __builtin_amdgcn_mfma_f32_16x16x32_bf16(af[mi], bl[ni], acc[mi][ni], 0, 0, 0);
#pragma unroll
            for (int mi = 0; mi < 4; ++mi)
#pragma unroll
                for (int ni = 0; ni < 2; ++ni)
                    acc[mi][ni] = __builtin_amdgcn_mfma_f32_16x16x32_bf16(al[mi], bh[ni], acc[mi][ni], 0, 0, 0);
            bh[0] = bhN[0]; bh[1] = bhN[1]; bl[0] = blN[0]; bl[1] = blN[1];
        }
    }
    // epilogue 1 -> LDS (bf16, swizzled)
#pragma unroll
    for (int ni = 0; ni < 2; ++ni) {
        float bb = bc[cb + ni * 16 + l15];
#pragma unroll
        for (int mi = 0; mi < 4; ++mi)
#pragma unroll
            for (int r = 0; r < 4; ++r) {
                int row = mi * 16 + l4 * 4 + r;
                int colx = (cb + ni * 16 + l15) ^ ((row & 7) << 3);
                float v = acc[mi][ni][r] + bb;
                v = v > 0.f ? v : ALPHA * v;
                hbuf[row][colx] = f2bf(v);
            }
    }
    __syncthreads();

    // ================= stage 2: K=256, A=h1 (LDS bf16), B=W2 hi/lo (2-pass) =================
#pragma unroll
    for (int mi = 0; mi < 4; ++mi)
#pragma unroll
        for (int ni = 0; ni < 2; ++ni) acc[mi][ni] = f32x4{0.f, 0.f, 0.f, 0.f};

    {
        bf16x8 bh[2], bl[2];
#pragma unroll
        for (int ni = 0; ni < 2; ++ni) {
            bh[ni] = *reinterpret_cast<const bf16x8*>(&W2Hi[(size_t)bcol[ni] * 256 + koff]);
            bl[ni] = *reinterpret_cast<const bf16x8*>(&W2Lo[(size_t)bcol[ni] * 256 + koff]);
        }
#pragma unroll
        for (int ks = 0; ks < 8; ++ks) {
            const int k0 = ks * 32;
            bf16x8 a[4];
#pragma unroll
            for (int mi = 0; mi < 4; ++mi) {
                int row = mi * 16 + l15;
                a[mi] = *reinterpret_cast<const bf16x8*>(&hbuf[row][(k0 + koff) ^ ((row & 7) << 3)]);
            }
            bf16x8 bhN[2] = {bh[0], bh[1]}, blN[2] = {bl[0], bl[1]};
            if (ks < 7) {
#pragma unroll
                for (int ni = 0; ni < 2; ++ni) {
                    bhN[ni] = *reinterpret_cast<const bf16x8*>(&W2Hi[(size_t)bcol[ni] * 256 + k0 + 32 + koff]);
                    blN[ni] = *reinterpret_cast<const bf16x8*>(&W2Lo[(size_t)bcol[ni] * 256 + k0 + 32 + koff]);
                }
            }
#pragma unroll
            for (int mi = 0; mi < 4; ++mi)
#pragma unroll
                for (int ni = 0; ni < 2; ++ni)
                    acc[mi][ni] = __builtin_amdgcn_mfma_f32_16x16x32_bf16(a[mi], bh[ni], acc[mi][ni], 0, 0, 0);
#pragma unroll
            for (int mi = 0; mi < 4; ++mi)
#pragma unroll
                for (int ni = 0; ni < 2; ++ni)
                    acc[mi][ni] = __builtin_amdgcn_mfma_f32_16x16x32_bf16(a[mi], bl[ni], acc[mi][ni], 0, 0, 0);
            bh[0] = bhN[0]; bh[1] = bhN[1]; bl[0] = blN[0]; bl[1] = blN[1];
        }
    }
    __syncthreads();   // all h1 reads done
    // epilogue 2 -> overwrite LDS
#pragma unroll
    for (int ni = 0; ni < 2; ++ni) {
        float bb = b2[cb + ni * 16 + l15];
#pragma unroll
        for (int mi = 0; mi < 4; ++mi)
#pragma unroll
            for (int r = 0; r < 4; ++r) {
                int row = mi * 16 + l4 * 4 + r;
                int colx = (cb + ni * 16 + l15) ^ ((row & 7) << 3);
                float v = acc[mi][ni][r] + bb;
                v = v > 0.f ? v : ALPHA * v;
                hbuf[row][colx] = f2bf(v);
            }
    }
    __syncthreads();

    // ================= stage 3: K=256, A=h2 (LDS), B=W3 hi/lo (2-pass) + head =================
#pragma unroll
    for (int mi = 0; mi < 4; ++mi)
#pragma unroll
        for (int ni = 0; ni < 2; ++ni) acc[mi][ni] = f32x4{0.f, 0.f, 0.f, 0.f};

    {
        bf16x8 bh[2], bl[2];
#pragma unroll
        for (int ni = 0; ni < 2; ++ni) {
            bh[ni] = *reinterpret_cast<const bf16x8*>(&W3Hi[(size_t)bcol[ni] * 256 + koff]);
            bl[ni] = *reinterpret_cast<const bf16x8*>(&W3Lo[(size_t)bcol[ni] * 256 + koff]);
        }
#pragma unroll
        for (int ks = 0; ks < 8; ++ks) {
            const int k0 = ks * 32;
            bf16x8 a[4];
#pragma unroll
            for (int mi = 0; mi < 4; ++mi) {
                int row = mi * 16 + l15;
                a[mi] = *reinterpret_cast<const bf16x8*>(&hbuf[row][(k0 + koff) ^ ((row & 7) << 3)]);
            }
            bf16x8 bhN[2] = {bh[0], bh[1]}, blN[2] = {bl[0], bl[1]};
            if (ks < 7) {
#pragma unroll
                for (int ni = 0; ni < 2; ++ni) {
                    bhN[ni] = *reinterpret_cast<const bf16x8*>(&W3Hi[(size_t)bcol[ni] * 256 + k0 + 32 + koff]);
                    blN[ni] = *reinterpret_cast<const bf16x8*>(&W3Lo[(size_t)bcol[ni] * 256 + k0 + 32 + koff]);
                }
            }
#pragma unroll
            for (int mi = 0; mi < 4; ++mi)
#pragma unroll
                for (int ni = 0; ni < 2; ++ni)
                    acc[mi][ni] = __builtin_amdgcn_mfma_f32_16x16x32_bf16(a[mi], bh[ni], acc[mi][ni], 0, 0, 0);
#pragma unroll
            for (int mi = 0; mi < 4; ++mi)
#pragma unroll
                for (int ni = 0; ni < 2; ++ni)
                    acc[mi][ni] = __builtin_amdgcn_mfma_f32_16x16x32_bf16(a[mi], bl[ni], acc[mi][ni], 0, 0, 0);
            bh[0] = bhN[0]; bh[1] = bhN[1]; bl[0] = blN[0]; bl[1] = blN[1];
        }
    }

    // head: out[m] = sum_n leaky(h3[m,n]) * wo[n]  (+ bo once per row, from wc==0)
    float bn[2], wn[2];
#pragma unroll
    for (int ni = 0; ni < 2; ++ni) {
        int gn = cb + ni * 16 + l15;
        bn[ni] = b3[gn];
        wn[ni] = wo[gn];
    }
    float badd = (wc == 0) ? bo[0] : 0.f;
#pragma unroll
    for (int mi = 0; mi < 4; ++mi) {
#pragma unroll
        for (int r = 0; r < 4; ++r) {
            float p = 0.f;
#pragma unroll
            for (int ni = 0; ni < 2; ++ni) {
                float v = acc[mi][ni][r] + bn[ni];
                v = v > 0.f ? v : ALPHA * v;
                p += v * wn[ni];
            }
#pragma unroll
            for (int off = 1; off < 16; off <<= 1) p += __shfl_xor(p, off, 16);
            int gm = m0 + mi * 16 + l4 * 4 + r;
            if (l15 == 0 && gm < M) atomicAdd(&outv[gm], p + badd);
        }
    }
}

// ---------------- launch ----------------

extern "C" void kernel_launch(void* const* d_in, const int* in_sizes, int n_in,
                              void* d_out, int out_size, void* d_ws, size_t ws_size,
                              hipStream_t stream) {
    const float* x  = (const float*)d_in[0];
    const int*   ei = (const int*)d_in[1];
    const float* Wg = (const float*)d_in[2];
    const float* bg = (const float*)d_in[3];
    const float* W1 = (const float*)d_in[4];
    const float* b1 = (const float*)d_in[5];
    const float* W2 = (const float*)d_in[6];
    const float* b2 = (const float*)d_in[7];
    const float* W3 = (const float*)d_in[8];
    const float* b3 = (const float*)d_in[9];
    const float* Wo = (const float*)d_in[10];
    const float* bo = (const float*)d_in[11];
    float* out = (float*)d_out;

    const int N = in_sizes[0] / 128;   // 50000
    const int E = in_sizes[1] / 2;     // 800000

    char* ws = (char*)d_ws;
    unsigned* xs     = (unsigned*)ws; ws += (size_t)N * 64 * 4;
    unsigned* aggHi  = (unsigned*)ws; ws += (size_t)N * 64 * 4;
    unsigned* aggLo  = (unsigned*)ws; ws += (size_t)N * 64 * 4;
    int* col   = (int*)ws;    ws += (size_t)E * 4;
    int* cnt   = (int*)ws;    ws += (size_t)N * 4;
    int* cursor= (int*)ws;    ws += 64;              // contiguous with cnt -> one memset
    int* roff  = (int*)ws;    ws += (size_t)(N + 64) * 4;
    float* dinv= (float*)ws;  ws += (size_t)N * 4;
    float* Wc  = (float*)ws;  ws += 128 * 256 * 4;
    float* bc  = (float*)ws;  ws += 256 * 4;
    unsigned short* WcThi = (unsigned short*)ws; ws += 256 * 128 * 2;
    unsigned short* WcTlo = (unsigned short*)ws; ws += 256 * 128 * 2;
    unsigned short* W2Thi = (unsigned short*)ws; ws += 256 * 256 * 2;
    unsigned short* W2Tlo = (unsigned short*)ws; ws += 256 * 256 * 2;
    unsigned short* W3Thi = (unsigned short*)ws; ws += 256 * 256 * 2;
    unsigned short* W3Tlo = (unsigned short*)ws; ws += 256 * 256 * 2;

    hipMemsetAsync(cnt, 0, (size_t)N * 4 + 64, stream);   // cnt + cursor
    hipMemsetAsync(out, 0, (size_t)N * 4, stream);        // head accumulates

    deg_kernel  <<<(E + 255) / 256, 256, 0, stream>>>(ei, cnt, E);
    alloc_kernel<<<(N + 255) / 256, 256, 0, stream>>>(cnt, roff, dinv, cursor, N);
    fill_kernel <<<(E + 255) / 256, 256, 0, stream>>>(ei, roff, col, E);
    xsconv_kernel<<<(N * 32 + 255) / 256, 256, 0, stream>>>((const float4*)x, dinv, (uint2*)xs, N * 32);
    agg_kernel  <<<(N + 3) / 4, 256, 0, stream>>>(xs, col, roff, cnt, dinv, aggHi, aggLo, N);

    wcbc_kernel<<<129, 256, 0, stream>>>(Wg, bg, W1, b1, Wc, bc);
    tsplit_kernel<<<(128 * 256 + 255) / 256, 256, 0, stream>>>(Wc, WcThi, WcTlo, 128, 256);
    tsplit_kernel<<<(256 * 256 + 255) / 256, 256, 0, stream>>>(W2, W2Thi, W2Tlo, 256, 256);
    tsplit_kernel<<<(256 * 256 + 255) / 256, 256, 0, stream>>>(W3, W3Thi, W3Tlo, 256, 256);

    mlp_fused<<<(N + 63) / 64, 512, 0, stream>>>(
        (const unsigned short*)aggHi, (const unsigned short*)aggLo,
        WcThi, WcTlo, W2Thi, W2Tlo, W3Thi, W3Tlo,
        bc, b2, b3, Wo, bo, out, N);
}

// Round 7
// 273.350 us; speedup vs baseline: 1.0552x; 1.0465x over previous
//
#include <hip/hip_runtime.h>
#include <hip/hip_bf16.h>

#define ALPHA 0.1f

using bf16x8 = __attribute__((ext_vector_type(8))) short;
using f32x4  = __attribute__((ext_vector_type(4))) float;

__device__ __forceinline__ unsigned short f2bf(float f) {
    unsigned u = __builtin_bit_cast(unsigned, f);
    u += 0x7fff + ((u >> 16) & 1);               // round-to-nearest-even
    return (unsigned short)(u >> 16);
}
__device__ __forceinline__ float bf2f(unsigned short h) {
    unsigned u = ((unsigned)h) << 16;
    return __builtin_bit_cast(float, u);
}
__device__ __forceinline__ float bflo(unsigned v) {
    return __builtin_bit_cast(float, v << 16);
}
__device__ __forceinline__ float bfhi(unsigned v) {
    return __builtin_bit_cast(float, v & 0xffff0000u);
}

// ---------------- edge preprocessing ----------------

__global__ void deg_kernel(const int* __restrict__ ei, int* __restrict__ cnt, int E) {
    int e = blockIdx.x * blockDim.x + threadIdx.x;
    if (e >= E) return;
    atomicAdd(&cnt[ei[E + e]], 1);
}

// per-wave atomic segment allocator + dinv (segments need only be contiguous, not ordered)
__global__ void alloc_kernel(const int* __restrict__ cnt, int* __restrict__ roff,
                             float* __restrict__ dinv, int* __restrict__ cursor, int N) {
    int i = blockIdx.x * blockDim.x + threadIdx.x;
    int lane = threadIdx.x & 63;
    int c = (i < N) ? cnt[i] : 0;
    if (i < N) dinv[i] = 1.0f / sqrtf((float)(c + 1));   // +1 self loop
    int pre = c;
#pragma unroll
    for (int off = 1; off < 64; off <<= 1) {
        int t = __shfl_up(pre, off, 64);
        if (lane >= off) pre += t;
    }
    int total = __shfl(pre, 63, 64);
    int base = 0;
    if (lane == 0) base = atomicAdd(cursor, total);
    base = __shfl(base, 0, 64);
    if (i < N) roff[i] = base + pre - c;
}

// claim slot directly from roff (roff[d] ends at segment END = start + cnt[d])
__global__ void fill_kernel(const int* __restrict__ ei, int* __restrict__ roff,
                            int* __restrict__ col, int E) {
    int e = blockIdx.x * blockDim.x + threadIdx.x;
    if (e >= E) return;
    int s = ei[e], d = ei[E + e];
    int pos = atomicAdd(&roff[d], 1);
    col[pos] = s;
}

// ---------------- xs = bf16(dinv[n] * x[n])  [N][128] packed as uint pairs ----------------

__global__ void xsconv_kernel(const float4* __restrict__ x4, const float* __restrict__ dinv,
                              uint2* __restrict__ xs, int total) {   // total = N*32
    int i = blockIdx.x * blockDim.x + threadIdx.x;
    if (i >= total) return;
    float di = dinv[i >> 5];
    float4 v = x4[i];
    uint2 o;
    o.x = (unsigned)f2bf(di * v.x) | ((unsigned)f2bf(di * v.y) << 16);
    o.y = (unsigned)f2bf(di * v.z) | ((unsigned)f2bf(di * v.w) << 16);
    xs[i] = o;
}

// ---------------- aggregation: one wave per node, bf16 gather, bf16 output ----------------

__global__ void agg_kernel(const unsigned* __restrict__ xs, const int* __restrict__ col,
                           const int* __restrict__ roff, const int* __restrict__ cnt,
                           const float* __restrict__ dinv,
                           unsigned* __restrict__ aggp, int N) {
    int w = (blockIdx.x * blockDim.x + threadIdx.x) >> 6;
    int lane = threadIdx.x & 63;
    if (w >= N) return;
    float di = dinv[w];
    unsigned vself = xs[(size_t)w * 64 + lane];
    float ax = bflo(vself), ay = bfhi(vself);      // self term
    int e = roff[w];            // segment end (after fill's claims)
    int s = e - cnt[w];
    int j = s;
    for (; j + 4 <= e; j += 4) {
        int c0 = col[j], c1 = col[j + 1], c2 = col[j + 2], c3 = col[j + 3];
        unsigned v0 = xs[(size_t)c0 * 64 + lane];
        unsigned v1 = xs[(size_t)c1 * 64 + lane];
        unsigned v2 = xs[(size_t)c2 * 64 + lane];
        unsigned v3 = xs[(size_t)c3 * 64 + lane];
        ax += bflo(v0) + bflo(v1) + bflo(v2) + bflo(v3);
        ay += bfhi(v0) + bfhi(v1) + bfhi(v2) + bfhi(v3);
    }
    for (; j < e; ++j) {
        unsigned v = xs[(size_t)col[j] * 64 + lane];
        ax += bflo(v);
        ay += bfhi(v);
    }
    float g0 = di * ax, g1 = di * ay;
    aggp[(size_t)w * 64 + lane] = (unsigned)f2bf(g0) | ((unsigned)f2bf(g1) << 16);
}

// ---------------- fold W_gcn@W1 -> Wc [128,256], bc = b_gcn@W1 + b1 ----------------

__global__ void wcbc_kernel(const float* __restrict__ Wg, const float* __restrict__ bg,
                            const float* __restrict__ W1, const float* __restrict__ b1,
                            float* __restrict__ Wc, float* __restrict__ bc) {
    int n = threadIdx.x;
    int m = blockIdx.x;
    if (m < 128) {
        float acc = 0.f;
#pragma unroll 8
        for (int k = 0; k < 512; ++k) acc += Wg[m * 512 + k] * W1[k * 256 + n];
        Wc[m * 256 + n] = acc;
    } else {
        float acc = b1[n];
#pragma unroll 8
        for (int k = 0; k < 512; ++k) acc += bg[k] * W1[k * 256 + n];
        bc[n] = acc;
    }
}

// ---------------- transpose+split weights: W[K][Nn] fp32 -> Wt_hi/lo [Nn][K] bf16 ----------------

__global__ void tsplit_kernel(const float* __restrict__ W, unsigned short* __restrict__ hi,
                              unsigned short* __restrict__ lo, int K, int Nn) {
    int idx = blockIdx.x * blockDim.x + threadIdx.x;
    if (idx >= K * Nn) return;
    int n = idx / K, k = idx - n * K;
    float v = W[k * Nn + n];
    unsigned short h = f2bf(v);
    hi[idx] = h;
    lo[idx] = f2bf(v - bf2f(h));
}

// ---------------- fused MLP: agg -> h1 -> h2 -> h3 -> head, one block per 64 rows ----------------
// 8 waves = 8 col-groups of 32; wave tile 64x32 = 4x2 frags of 16x16x32.
// Depth-2 double-buffered B prefetch: slot ks&1 consumed at ks, refilled for ks+2
// AFTER its MFMAs -> each load in flight across a full MFMA iteration (+TLP).
// A: stage1 global bf16, prefetched 1 iter ahead; stages 2/3 from LDS (JIT ds_read).
// h1/h2 in one 32KB LDS buffer (bf16, XOR-swizzled col ^= (row&7)*8).

__global__ __launch_bounds__(512, 4) void mlp_fused(
    const unsigned short* __restrict__ A,
    const unsigned short* __restrict__ WcHi, const unsigned short* __restrict__ WcLo,
    const unsigned short* __restrict__ W2Hi, const unsigned short* __restrict__ W2Lo,
    const unsigned short* __restrict__ W3Hi, const unsigned short* __restrict__ W3Lo,
    const float* __restrict__ bc, const float* __restrict__ b2, const float* __restrict__ b3,
    const float* __restrict__ wo, const float* __restrict__ bo,
    float* __restrict__ outv, int M)
{
    __shared__ unsigned short hbuf[64][256];   // 32 KB, swizzled

    const int tid  = threadIdx.x;
    const int lane = tid & 63;
    const int wc   = tid >> 6;                 // col-group (0..7)
    const int l15 = lane & 15, l4 = lane >> 4;
    const int koff = l4 * 8;
    const int m0 = blockIdx.x * 64;
    const int cb = wc * 32;

    f32x4 acc[4][2];

    size_t arow[4];
#pragma unroll
    for (int mi = 0; mi < 4; ++mi) {
        int gm = m0 + mi * 16 + l15;
        arow[mi] = (size_t)(gm < M ? gm : M - 1);
    }

    // ================= stage 1: K=128, A=agg bf16, B=Wc hi/lo (2-pass) =================
#pragma unroll
    for (int mi = 0; mi < 4; ++mi)
#pragma unroll
        for (int ni = 0; ni < 2; ++ni) acc[mi][ni] = f32x4{0.f, 0.f, 0.f, 0.f};

    {
        const unsigned short* BH[2];
        const unsigned short* BL[2];
#pragma unroll
        for (int ni = 0; ni < 2; ++ni) {
            BH[ni] = WcHi + (size_t)(cb + ni * 16 + l15) * 128 + koff;
            BL[ni] = WcLo + (size_t)(cb + ni * 16 + l15) * 128 + koff;
        }
        bf16x8 bh[2][2], bl[2][2], af[2][4];
#pragma unroll
        for (int ni = 0; ni < 2; ++ni) {
            bh[0][ni] = *reinterpret_cast<const bf16x8*>(BH[ni]);
            bl[0][ni] = *reinterpret_cast<const bf16x8*>(BL[ni]);
            bh[1][ni] = *reinterpret_cast<const bf16x8*>(BH[ni] + 32);
            bl[1][ni] = *reinterpret_cast<const bf16x8*>(BL[ni] + 32);
        }
#pragma unroll
        for (int mi = 0; mi < 4; ++mi)
            af[0][mi] = *reinterpret_cast<const bf16x8*>(&A[arow[mi] * 128 + koff]);

#pragma unroll
        for (int ks = 0; ks < 4; ++ks) {
            const int cur = ks & 1;
            if (ks < 3) {
#pragma unroll
                for (int mi = 0; mi < 4; ++mi)
                    af[cur ^ 1][mi] = *reinterpret_cast<const bf16x8*>(&A[arow[mi] * 128 + (ks + 1) * 32 + koff]);
            }
#pragma unroll
            for (int mi = 0; mi < 4; ++mi)
#pragma unroll
                for (int ni = 0; ni < 2; ++ni)
                    acc[mi][ni] = __builtin_amdgcn_mfma_f32_16x16x32_bf16(af[cur][mi], bh[cur][ni], acc[mi][ni], 0, 0, 0);
#pragma unroll
            for (int mi = 0; mi < 4; ++mi)
#pragma unroll
                for (int ni = 0; ni < 2; ++ni)
                    acc[mi][ni] = __builtin_amdgcn_mfma_f32_16x16x32_bf16(af[cur][mi], bl[cur][ni], acc[mi][ni], 0, 0, 0);
            if (ks < 2) {
#pragma unroll
                for (int ni = 0; ni < 2; ++ni) {
                    bh[cur][ni] = *reinterpret_cast<const bf16x8*>(BH[ni] + (ks + 2) * 32);
                    bl[cur][ni] = *reinterpret_cast<const bf16x8*>(BL[ni] + (ks + 2) * 32);
                }
            }
        }
    }
    // epilogue 1 -> LDS (bf16, swizzled)
#pragma unroll
    for (int ni = 0; ni < 2; ++ni) {
        float bb = bc[cb + ni * 16 + l15];
#pragma unroll
        for (int mi = 0; mi < 4; ++mi)
#pragma unroll
            for (int r = 0; r < 4; ++r) {
                int row = mi * 16 + l4 * 4 + r;
                int colx = (cb + ni * 16 + l15) ^ ((row & 7) << 3);
                float v = acc[mi][ni][r] + bb;
                v = v > 0.f ? v : ALPHA * v;
                hbuf[row][colx] = f2bf(v);
            }
    }
    __syncthreads();

    // ================= stage 2: K=256, A=h1 (LDS), B=W2 hi/lo (2-pass) =================
#pragma unroll
    for (int mi = 0; mi < 4; ++mi)
#pragma unroll
        for (int ni = 0; ni < 2; ++ni) acc[mi][ni] = f32x4{0.f, 0.f, 0.f, 0.f};

    {
        const unsigned short* BH[2];
        const unsigned short* BL[2];
#pragma unroll
        for (int ni = 0; ni < 2; ++ni) {
            BH[ni] = W2Hi + (size_t)(cb + ni * 16 + l15) * 256 + koff;
            BL[ni] = W2Lo + (size_t)(cb + ni * 16 + l15) * 256 + koff;
        }
        bf16x8 bh[2][2], bl[2][2];
#pragma unroll
        for (int ni = 0; ni < 2; ++ni) {
            bh[0][ni] = *reinterpret_cast<const bf16x8*>(BH[ni]);
            bl[0][ni] = *reinterpret_cast<const bf16x8*>(BL[ni]);
            bh[1][ni] = *reinterpret_cast<const bf16x8*>(BH[ni] + 32);
            bl[1][ni] = *reinterpret_cast<const bf16x8*>(BL[ni] + 32);
        }
#pragma unroll
        for (int ks = 0; ks < 8; ++ks) {
            const int cur = ks & 1;
            bf16x8 a[4];
#pragma unroll
            for (int mi = 0; mi < 4; ++mi) {
                int row = mi * 16 + l15;
                a[mi] = *reinterpret_cast<const bf16x8*>(&hbuf[row][(ks * 32 + koff) ^ ((row & 7) << 3)]);
            }
#pragma unroll
            for (int mi = 0; mi < 4; ++mi)
#pragma unroll
                for (int ni = 0; ni < 2; ++ni)
                    acc[mi][ni] = __builtin_amdgcn_mfma_f32_16x16x32_bf16(a[mi], bh[cur][ni], acc[mi][ni], 0, 0, 0);
#pragma unroll
            for (int mi = 0; mi < 4; ++mi)
#pragma unroll
                for (int ni = 0; ni < 2; ++ni)
                    acc[mi][ni] = __builtin_amdgcn_mfma_f32_16x16x32_bf16(a[mi], bl[cur][ni], acc[mi][ni], 0, 0, 0);
            if (ks < 6) {
#pragma unroll
                for (int ni = 0; ni < 2; ++ni) {
                    bh[cur][ni] = *reinterpret_cast<const bf16x8*>(BH[ni] + (ks + 2) * 32);
                    bl[cur][ni] = *reinterpret_cast<const bf16x8*>(BL[ni] + (ks + 2) * 32);
                }
            }
        }
    }
    __syncthreads();   // all h1 reads done
    // epilogue 2 -> overwrite LDS
#pragma unroll
    for (int ni = 0; ni < 2; ++ni) {
        float bb = b2[cb + ni * 16 + l15];
#pragma unroll
        for (int mi = 0; mi < 4; ++mi)
#pragma unroll
            for (int r = 0; r < 4; ++r) {
                int row = mi * 16 + l4 * 4 + r;
                int colx = (cb + ni * 16 + l15) ^ ((row & 7) << 3);
                float v = acc[mi][ni][r] + bb;
                v = v > 0.f ? v : ALPHA * v;
                hbuf[row][colx] = f2bf(v);
            }
    }
    __syncthreads();

    // ================= stage 3: K=256, A=h2 (LDS), B=W3 hi/lo (2-pass) + head =================
#pragma unroll
    for (int mi = 0; mi < 4; ++mi)
#pragma unroll
        for (int ni = 0; ni < 2; ++ni) acc[mi][ni] = f32x4{0.f, 0.f, 0.f, 0.f};

    {
        const unsigned short* BH[2];
        const unsigned short* BL[2];
#pragma unroll
        for (int ni = 0; ni < 2; ++ni) {
            BH[ni] = W3Hi + (size_t)(cb + ni * 16 + l15) * 256 + koff;
            BL[ni] = W3Lo + (size_t)(cb + ni * 16 + l15) * 256 + koff;
        }
        bf16x8 bh[2][2], bl[2][2];
#pragma unroll
        for (int ni = 0; ni < 2; ++ni) {
            bh[0][ni] = *reinterpret_cast<const bf16x8*>(BH[ni]);
            bl[0][ni] = *reinterpret_cast<const bf16x8*>(BL[ni]);
            bh[1][ni] = *reinterpret_cast<const bf16x8*>(BH[ni] + 32);
            bl[1][ni] = *reinterpret_cast<const bf16x8*>(BL[ni] + 32);
        }
#pragma unroll
        for (int ks = 0; ks < 8; ++ks) {
            const int cur = ks & 1;
            bf16x8 a[4];
#pragma unroll
            for (int mi = 0; mi < 4; ++mi) {
                int row = mi * 16 + l15;
                a[mi] = *reinterpret_cast<const bf16x8*>(&hbuf[row][(ks * 32 + koff) ^ ((row & 7) << 3)]);
            }
#pragma unroll
            for (int mi = 0; mi < 4; ++mi)
#pragma unroll
                for (int ni = 0; ni < 2; ++ni)
                    acc[mi][ni] = __builtin_amdgcn_mfma_f32_16x16x32_bf16(a[mi], bh[cur][ni], acc[mi][ni], 0, 0, 0);
#pragma unroll
            for (int mi = 0; mi < 4; ++mi)
#pragma unroll
                for (int ni = 0; ni < 2; ++ni)
                    acc[mi][ni] = __builtin_amdgcn_mfma_f32_16x16x32_bf16(a[mi], bl[cur][ni], acc[mi][ni], 0, 0, 0);
            if (ks < 6) {
#pragma unroll
                for (int ni = 0; ni < 2; ++ni) {
                    bh[cur][ni] = *reinterpret_cast<const bf16x8*>(BH[ni] + (ks + 2) * 32);
                    bl[cur][ni] = *reinterpret_cast<const bf16x8*>(BL[ni] + (ks + 2) * 32);
                }
            }
        }
    }

    // head: out[m] = sum_n leaky(h3[m,n]) * wo[n]  (+ bo once per row, from wc==0)
    float bn[2], wn[2];
#pragma unroll
    for (int ni = 0; ni < 2; ++ni) {
        int gn = cb + ni * 16 + l15;
        bn[ni] = b3[gn];
        wn[ni] = wo[gn];
    }
    float badd = (wc == 0) ? bo[0] : 0.f;
#pragma unroll
    for (int mi = 0; mi < 4; ++mi) {
#pragma unroll
        for (int r = 0; r < 4; ++r) {
            float p = 0.f;
#pragma unroll
            for (int ni = 0; ni < 2; ++ni) {
                float v = acc[mi][ni][r] + bn[ni];
                v = v > 0.f ? v : ALPHA * v;
                p += v * wn[ni];
            }
#pragma unroll
            for (int off = 1; off < 16; off <<= 1) p += __shfl_xor(p, off, 16);
            int gm = m0 + mi * 16 + l4 * 4 + r;
            if (l15 == 0 && gm < M) atomicAdd(&outv[gm], p + badd);
        }
    }
}

// ---------------- launch ----------------

extern "C" void kernel_launch(void* const* d_in, const int* in_sizes, int n_in,
                              void* d_out, int out_size, void* d_ws, size_t ws_size,
                              hipStream_t stream) {
    const float* x  = (const float*)d_in[0];
    const int*   ei = (const int*)d_in[1];
    const float* Wg = (const float*)d_in[2];
    const float* bg = (const float*)d_in[3];
    const float* W1 = (const float*)d_in[4];
    const float* b1 = (const float*)d_in[5];
    const float* W2 = (const float*)d_in[6];
    const float* b2 = (const float*)d_in[7];
    const float* W3 = (const float*)d_in[8];
    const float* b3 = (const float*)d_in[9];
    const float* Wo = (const float*)d_in[10];
    const float* bo = (const float*)d_in[11];
    float* out = (float*)d_out;

    const int N = in_sizes[0] / 128;   // 50000
    const int E = in_sizes[1] / 2;     // 800000

    char* ws = (char*)d_ws;
    unsigned* xs     = (unsigned*)ws; ws += (size_t)N * 64 * 4;
    unsigned* aggp   = (unsigned*)ws; ws += (size_t)N * 64 * 4;
    int* col   = (int*)ws;    ws += (size_t)E * 4;
    int* cnt   = (int*)ws;    ws += (size_t)N * 4;
    int* cursor= (int*)ws;    ws += 64;              // contiguous with cnt -> one memset
    int* roff  = (int*)ws;    ws += (size_t)(N + 64) * 4;
    float* dinv= (float*)ws;  ws += (size_t)N * 4;
    float* Wc  = (float*)ws;  ws += 128 * 256 * 4;
    float* bc  = (float*)ws;  ws += 256 * 4;
    unsigned short* WcThi = (unsigned short*)ws; ws += 256 * 128 * 2;
    unsigned short* WcTlo = (unsigned short*)ws; ws += 256 * 128 * 2;
    unsigned short* W2Thi = (unsigned short*)ws; ws += 256 * 256 * 2;
    unsigned short* W2Tlo = (unsigned short*)ws; ws += 256 * 256 * 2;
    unsigned short* W3Thi = (unsigned short*)ws; ws += 256 * 256 * 2;
    unsigned short* W3Tlo = (unsigned short*)ws; ws += 256 * 256 * 2;

    hipMemsetAsync(cnt, 0, (size_t)N * 4 + 64, stream);   // cnt + cursor
    hipMemsetAsync(out, 0, (size_t)N * 4, stream);        // head accumulates

    deg_kernel  <<<(E + 255) / 256, 256, 0, stream>>>(ei, cnt, E);
    alloc_kernel<<<(N + 255) / 256, 256, 0, stream>>>(cnt, roff, dinv, cursor, N);
    fill_kernel <<<(E + 255) / 256, 256, 0, stream>>>(ei, roff, col, E);
    xsconv_kernel<<<(N * 32 + 255) / 256, 256, 0, stream>>>((const float4*)x, dinv, (uint2*)xs, N * 32);
    agg_kernel  <<<(N + 3) / 4, 256, 0, stream>>>(xs, col, roff, cnt, dinv, aggp, N);

    wcbc_kernel<<<129, 256, 0, stream>>>(Wg, bg, W1, b1, Wc, bc);
    tsplit_kernel<<<(128 * 256 + 255) / 256, 256, 0, stream>>>(Wc, WcThi, WcTlo, 128, 256);
    tsplit_kernel<<<(256 * 256 + 255) / 256, 256, 0, stream>>>(W2, W2Thi, W2Tlo, 256, 256);
    tsplit_kernel<<<(256 * 256 + 255) / 256, 256, 0, stream>>>(W3, W3Thi, W3Tlo, 256, 256);

    mlp_fused<<<(N + 63) / 64, 512, 0, stream>>>(
        (const unsigned short*)aggp,
        WcThi, WcTlo, W2Thi, W2Tlo, W3Thi, W3Tlo,
        bc, b2, b3, Wo, bo, out, N);
}